// Round 4
// baseline (3572.105 us; speedup 1.0000x reference)
//
#include <hip/hip_runtime.h>
#include <hip/hip_bf16.h>

#define H 16
#define F_IN 58
#define NPB 16     // nodes per block in t0 (256 threads / 16 lanes)
#define SCH 6272   // max edges per stage chunk (LDS sort capacity)

static inline size_t align256(size_t x) { return (x + 255) & ~(size_t)255; }

__device__ inline float bf2f(__hip_bfloat16 h) { return __bfloat162float(h); }
__device__ inline float bfu2f(unsigned short u) {
    return __uint_as_float(((unsigned)u) << 16);
}

// ---------- dtype detection: int64 vs int32 edge_index ----------
__global__ void detect_kernel(const int* eidx32, int* flag) {
    __shared__ int any;
    if (threadIdx.x == 0) any = 0;
    __syncthreads();
    int nz = 0;
    for (int j = threadIdx.x; j < 1024; j += 256)
        nz |= (eidx32[2 * j + 1] != 0);
    if (nz) atomicOr(&any, 1);
    __syncthreads();
    if (threadIdx.x == 0) *flag = (any == 0) ? 1 : 0;  // all-zero odd words -> int64
}

__device__ inline int load_idx(const void* eidx, long i, int is64) {
    if (is64) return (int)((const long long*)eidx)[i];
    return ((const int*)eidx)[i];
}

// ---------- bucket counts (391 bins of 256 nodes) via LDS histogram ----------
__global__ void bcount_kernel(const void* eidx, int E, const int* flag64,
                              int n, int* bucketcnt) {
    __shared__ int hist[512];
    int is64 = *flag64;
    int B = (n + 255) >> 8;
    int tid = threadIdx.x;
    for (int j = tid; j < B; j += 256) hist[j] = 0;
    __syncthreads();
    int stride = gridDim.x * blockDim.x;
    for (int i = blockIdx.x * blockDim.x + tid; i < E; i += stride) {
        int d = load_idx(eidx, (long)E + i, is64);
        atomicAdd(&hist[d >> 8], 1);
    }
    __syncthreads();
    for (int j = tid; j < B; j += 256)
        if (hist[j]) atomicAdd(&bucketcnt[j], hist[j]);
}

// ---------- exclusive scan of bucket counts (single block, B <= 512) ----------
__global__ void bscan_kernel(const int* bucketcnt, int B, int E,
                             int* gcur, int* bucketbase) {
    __shared__ int tmp[512];
    int tid = threadIdx.x;
    int val = (tid < B) ? bucketcnt[tid] : 0;
    tmp[tid] = val;
    __syncthreads();
    for (int off = 1; off < 512; off <<= 1) {
        int t = (tid >= off) ? tmp[tid - off] : 0;
        __syncthreads();
        tmp[tid] += t;
        __syncthreads();
    }
    if (tid < B) {
        int ex = tmp[tid] - val;
        gcur[tid] = ex;
        bucketbase[tid] = ex;
    }
    if (tid == 0) bucketbase[B] = E;
}

// ---------- stage: LDS counting-sort each chunk by bucket, write coalesced runs ----------
__global__ void stage_kernel(const void* eidx, int E, const int* flag64,
                             int n, int* gcur, unsigned* staging) {
    __shared__ unsigned sorted[SCH];
    __shared__ unsigned short sbuck[SCH];
    __shared__ int hist[512];
    __shared__ int hbase[512];
    __shared__ int lofs[512];
    __shared__ int cursor[512];
    __shared__ int ps[256];

    int is64 = *flag64;
    int tid = threadIdx.x;
    int chunk = (E + gridDim.x - 1) / gridDim.x;
    int s0 = blockIdx.x * chunk;
    int s1 = min(E, s0 + chunk);
    int c = s1 - s0;
    if (c <= 0) return;

    for (int j = tid; j < 512; j += 256) { hist[j] = 0; cursor[j] = 0; }
    __syncthreads();

    // pass A: per-chunk bucket histogram
    for (int i = s0 + tid; i < s1; i += 256) {
        int d = load_idx(eidx, (long)E + i, is64);
        atomicAdd(&hist[d >> 8], 1);
    }
    __syncthreads();

    // pass B: reserve global run per bucket
    for (int j = tid; j < 512; j += 256) {
        int cc = hist[j];
        hbase[j] = cc ? atomicAdd(&gcur[j], cc) : 0;
    }

    // pass C: exclusive scan of hist -> lofs (512 bins, 256 threads)
    int a0 = hist[2 * tid], a1 = hist[2 * tid + 1];
    ps[tid] = a0 + a1;
    __syncthreads();
    for (int off = 1; off < 256; off <<= 1) {
        int t = (tid >= off) ? ps[tid - off] : 0;
        __syncthreads();
        ps[tid] += t;
        __syncthreads();
    }
    int ex = ps[tid] - (a0 + a1);
    lofs[2 * tid] = ex;
    lofs[2 * tid + 1] = ex + a0;
    __syncthreads();

    // pass D: scatter into LDS in bucket-sorted order
    for (int i = s0 + tid; i < s1; i += 256) {
        int s = load_idx(eidx, i, is64);
        int d = load_idx(eidx, (long)E + i, is64);
        int b = d >> 8;
        int loc = lofs[b] + atomicAdd(&cursor[b], 1);
        sorted[loc] = (unsigned)s | ((unsigned)(d & 255) << 17);
        sbuck[loc] = (unsigned short)b;
    }
    __syncthreads();

    // pass E: linear LDS read, coalesced run writes to global
    for (int i = tid; i < c; i += 256) {
        int b = sbuck[i];
        staging[hbase[b] + (i - lofs[b])] = sorted[i];
    }
}

// ---------- per-node degree -> dinv (from bucket-grouped staging) ----------
__global__ void deg_kernel(const unsigned* __restrict__ stg,
                           const int* __restrict__ bucketbase,
                           int n, float* __restrict__ dinv) {
    __shared__ int lcnt[256];
    int tid = threadIdx.x;
    int b = blockIdx.x;
    lcnt[tid] = 0;
    __syncthreads();
    int start = bucketbase[b];
    int cnt = bucketbase[b + 1] - start;
    for (int i = tid; i < cnt; i += 256)
        atomicAdd(&lcnt[stg[start + i] >> 17], 1);
    __syncthreads();
    int g = (b << 8) + tid;
    if (g < n) dinv[g] = rsqrtf((float)(lcnt[tid] + 1));
}

// ---------- layer 0 dense transform: hw0 = bf16(dinv * (x @ W0)) ----------
__global__ void t0_kernel(const float* __restrict__ x, const float* __restrict__ W0,
                          const float* __restrict__ dinv,
                          __hip_bfloat16* __restrict__ hw, int n) {
    __shared__ float Wl[F_IN * H];
    int tid = threadIdx.x;
    for (int j = tid; j < F_IN * H; j += 256) Wl[j] = W0[j];
    __syncthreads();
    int g = tid >> 4, f = tid & 15;
    int v = blockIdx.x * NPB + g;
    if (v >= n) return;
    const float* xr = x + (long)v * F_IN;
    float acc = 0.f;
#pragma unroll
    for (int k = 0; k < F_IN; ++k) acc += xr[k] * Wl[k * H + f];
    hw[v * H + f] = __float2bfloat16(acc * dinv[v]);
}

// ---------- aggregation: edge-parallel gather + LDS f32 atomics ----------
// One block = one 256-node bucket. hw holds dinv-scaled features (bf16).
// agg[v] = dinv[v] * (sum_src hw[src] + hw[v]); then bias/relu/jk/next-W.
__global__ __launch_bounds__(1024) void agg_kernel(
    const unsigned* __restrict__ stg, const int* __restrict__ bucketbase,
    const float* __restrict__ dinv, const __hip_bfloat16* __restrict__ hw,
    const float* __restrict__ bias, const float* __restrict__ Wnext,
    float* __restrict__ jk, __hip_bfloat16* __restrict__ hw_next,
    int n, int first, int has_next) {
    __shared__ float acc[256 * 17];   // padded stride 17: bank-conflict-free
    __shared__ float Wl[H * H];
    int tid = threadIdx.x;
    int b = blockIdx.x;
    if (has_next && tid < 256) Wl[tid] = Wnext[tid];
    for (int i = tid; i < 256 * 17; i += 1024) acc[i] = 0.f;
    __syncthreads();

    int start = bucketbase[b];
    int cnt = bucketbase[b + 1] - start;
    int q = tid >> 2;                 // edge slot 0..255
    int lq = (tid & 3) * 4;           // feature quad base: 0,4,8,12

    for (int it = 0; it < cnt; it += 512) {
        int e0 = it + q;
        int e1 = it + 256 + q;
        bool v0 = (e0 < cnt), v1 = (e1 < cnt);
        unsigned w0 = v0 ? stg[start + e0] : 0u;
        unsigned w1 = v1 ? stg[start + e1] : 0u;
        ushort4 u0, u1;
        if (v0) u0 = *(const ushort4*)((const unsigned short*)hw + ((w0 & 0x1FFFFu) * H + lq));
        if (v1) u1 = *(const ushort4*)((const unsigned short*)hw + ((w1 & 0x1FFFFu) * H + lq));
        if (v0) {
            float* a = &acc[(w0 >> 17) * 17 + lq];
            atomicAdd(a,     bfu2f(u0.x));
            atomicAdd(a + 1, bfu2f(u0.y));
            atomicAdd(a + 2, bfu2f(u0.z));
            atomicAdd(a + 3, bfu2f(u0.w));
        }
        if (v1) {
            float* a = &acc[(w1 >> 17) * 17 + lq];
            atomicAdd(a,     bfu2f(u1.x));
            atomicAdd(a + 1, bfu2f(u1.y));
            atomicAdd(a + 2, bfu2f(u1.z));
            atomicAdd(a + 3, bfu2f(u1.w));
        }
    }
    __syncthreads();

    // epilogue: 4 rounds of 64 nodes x 16 features
    int f = tid & 15;
    int nl = tid >> 4;                // 0..63
    int node0 = b << 8;
    for (int r = 0; r < 4; ++r) {
        int node = r * 64 + nl;
        int g = node0 + node;
        if (g < n) {
            float dv = dinv[g];
            float sum = acc[node * 17 + f] + bf2f(hw[(size_t)g * H + f]);
            float val = fmaxf(sum * dv + bias[f], 0.f);
            float jv = first ? val : fmaxf(jk[(size_t)g * H + f], val);
            jk[(size_t)g * H + f] = jv;
            if (has_next) {
                float acc2 = 0.f;
#pragma unroll
                for (int k = 0; k < H; ++k)
                    acc2 += __shfl(val, k, 16) * Wl[k * H + f];
                hw_next[(size_t)g * H + f] = __float2bfloat16(acc2 * dv);
            }
        }
    }
}

// ---------- final FC: out = jk @ fc_w + fc_b ----------
__global__ void fc_kernel(const float* __restrict__ jk, const float* __restrict__ fc_w,
                          const float* __restrict__ fc_b, float* __restrict__ out, int n) {
    __shared__ float w[H];
    __shared__ float b0;
    if (threadIdx.x < H) w[threadIdx.x] = fc_w[threadIdx.x];
    if (threadIdx.x == 0) b0 = fc_b[0];
    __syncthreads();
    int v = blockIdx.x * 256 + threadIdx.x;
    if (v >= n) return;
    const float4* r = (const float4*)(jk + (long)v * H);
    float4 a = r[0], b = r[1], c = r[2], d = r[3];
    float sum = a.x * w[0] + a.y * w[1] + a.z * w[2] + a.w * w[3]
              + b.x * w[4] + b.y * w[5] + b.z * w[6] + b.w * w[7]
              + c.x * w[8] + c.y * w[9] + c.z * w[10] + c.w * w[11]
              + d.x * w[12] + d.y * w[13] + d.z * w[14] + d.w * w[15];
    out[v] = sum + b0;
}

extern "C" void kernel_launch(void* const* d_in, const int* in_sizes, int n_in,
                              void* d_out, int out_size, void* d_ws, size_t ws_size,
                              hipStream_t stream) {
    const float* x    = (const float*)d_in[0];
    const void*  eidx = d_in[1];
    const float* W0   = (const float*)d_in[2];
    const float* Ws   = (const float*)d_in[3];
    const float* bs   = (const float*)d_in[4];
    const float* fc_w = (const float*)d_in[5];
    const float* fc_b = (const float*)d_in[6];

    int n = in_sizes[0] / F_IN;        // 100000
    int E = in_sizes[1] / 2;           // 3200000
    int L = in_sizes[4] / H;           // 10

    // workspace carve-up
    char* w = (char*)d_ws;
    size_t off = 0;
    float* dinv      = (float*)(w + off); off += align256((size_t)n * 4);
    int* bucketcnt   = (int*)(w + off); off += align256(512 * 4);
    int* bucketbase  = (int*)(w + off); off += align256(513 * 4);
    int* gcur        = (int*)(w + off); off += align256(512 * 4);
    int* flag64      = (int*)(w + off); off += align256(256);
    unsigned* stg    = (unsigned*)(w + off); off += align256((size_t)E * 4);
    __hip_bfloat16* hwA = (__hip_bfloat16*)(w + off); off += align256((size_t)n * H * 2);
    __hip_bfloat16* hwB = (__hip_bfloat16*)(w + off); off += align256((size_t)n * H * 2);
    float* jk        = (float*)(w + off); off += align256((size_t)n * H * 4);

    int NB = (n + 255) / 256;          // 391 buckets of 256 nodes

    hipMemsetAsync(bucketcnt, 0, 512 * 4, stream);
    detect_kernel<<<1, 256, 0, stream>>>((const int*)eidx, flag64);
    bcount_kernel<<<512, 256, 0, stream>>>(eidx, E, flag64, n, bucketcnt);
    bscan_kernel<<<1, 512, 0, stream>>>(bucketcnt, NB, E, gcur, bucketbase);
    int SG = (E + 6143) / 6144;        // chunk <= 6144 <= SCH
    stage_kernel<<<SG, 256, 0, stream>>>(eidx, E, flag64, n, gcur, stg);
    deg_kernel<<<NB, 256, 0, stream>>>(stg, bucketbase, n, dinv);

    int ngrid = (n + NPB - 1) / NPB;   // 6250
    t0_kernel<<<ngrid, 256, 0, stream>>>(x, W0, dinv, hwA, n);

    __hip_bfloat16* cur = hwA;
    __hip_bfloat16* nxt = hwB;
    for (int l = 0; l < L; ++l) {
        const float* bias  = bs + (size_t)l * H;
        const float* Wnext = (l < L - 1) ? (Ws + (size_t)l * H * H) : nullptr;
        agg_kernel<<<NB, 1024, 0, stream>>>(stg, bucketbase, dinv, cur, bias, Wnext,
                                            jk, nxt, n, (l == 0) ? 1 : 0,
                                            (l < L - 1) ? 1 : 0);
        __hip_bfloat16* t = cur; cur = nxt; nxt = t;
    }

    fc_kernel<<<NB, 256, 0, stream>>>(jk, fc_w, fc_b, (float*)d_out, n);
}

// Round 5
// 413.613 us; speedup vs baseline: 8.6363x; 8.6363x over previous
//
#include <hip/hip_runtime.h>
#include <hip/hip_bf16.h>

#define H 16
#define F_IN 58
#define NPB 16     // nodes per block in t0 (256 threads / 16 lanes)
#define SCH 6272   // max edges per stage chunk (LDS sort capacity)

static inline size_t align256(size_t x) { return (x + 255) & ~(size_t)255; }

__device__ inline float bf2f(__hip_bfloat16 h) { return __bfloat162float(h); }
__device__ inline float bfu2f(unsigned short u) {
    return __uint_as_float(((unsigned)u) << 16);
}

// ---------- dtype detection: int64 vs int32 edge_index ----------
__global__ void detect_kernel(const int* eidx32, int* flag) {
    __shared__ int any;
    if (threadIdx.x == 0) any = 0;
    __syncthreads();
    int nz = 0;
    for (int j = threadIdx.x; j < 1024; j += 256)
        nz |= (eidx32[2 * j + 1] != 0);
    if (nz) atomicOr(&any, 1);
    __syncthreads();
    if (threadIdx.x == 0) *flag = (any == 0) ? 1 : 0;  // all-zero odd words -> int64
}

__device__ inline int load_idx(const void* eidx, long i, int is64) {
    if (is64) return (int)((const long long*)eidx)[i];
    return ((const int*)eidx)[i];
}

// ---------- bucket counts (391 bins of 256 nodes) via LDS histogram ----------
__global__ void bcount_kernel(const void* eidx, int E, const int* flag64,
                              int n, int* bucketcnt) {
    __shared__ int hist[512];
    int is64 = *flag64;
    int B = (n + 255) >> 8;
    int tid = threadIdx.x;
    for (int j = tid; j < B; j += 256) hist[j] = 0;
    __syncthreads();
    int stride = gridDim.x * blockDim.x;
    for (int i = blockIdx.x * blockDim.x + tid; i < E; i += stride) {
        int d = load_idx(eidx, (long)E + i, is64);
        atomicAdd(&hist[d >> 8], 1);
    }
    __syncthreads();
    for (int j = tid; j < B; j += 256)
        if (hist[j]) atomicAdd(&bucketcnt[j], hist[j]);
}

// ---------- exclusive scan of bucket counts (single block, B <= 512) ----------
__global__ void bscan_kernel(const int* bucketcnt, int B, int E,
                             int* gcur, int* bucketbase) {
    __shared__ int tmp[512];
    int tid = threadIdx.x;
    int val = (tid < B) ? bucketcnt[tid] : 0;
    tmp[tid] = val;
    __syncthreads();
    for (int off = 1; off < 512; off <<= 1) {
        int t = (tid >= off) ? tmp[tid - off] : 0;
        __syncthreads();
        tmp[tid] += t;
        __syncthreads();
    }
    if (tid < B) {
        int ex = tmp[tid] - val;
        gcur[tid] = ex;
        bucketbase[tid] = ex;
    }
    if (tid == 0) bucketbase[B] = E;
}

// ---------- stage: LDS counting-sort each chunk by bucket, write coalesced runs ----------
__global__ void stage_kernel(const void* eidx, int E, const int* flag64,
                             int n, int* gcur, unsigned* staging) {
    __shared__ unsigned sorted[SCH];
    __shared__ unsigned short sbuck[SCH];
    __shared__ int hist[512];
    __shared__ int hbase[512];
    __shared__ int lofs[512];
    __shared__ int cursor[512];
    __shared__ int ps[256];

    int is64 = *flag64;
    int tid = threadIdx.x;
    int chunk = (E + gridDim.x - 1) / gridDim.x;
    int s0 = blockIdx.x * chunk;
    int s1 = min(E, s0 + chunk);
    int c = s1 - s0;
    if (c <= 0) return;

    for (int j = tid; j < 512; j += 256) { hist[j] = 0; cursor[j] = 0; }
    __syncthreads();

    // pass A: per-chunk bucket histogram
    for (int i = s0 + tid; i < s1; i += 256) {
        int d = load_idx(eidx, (long)E + i, is64);
        atomicAdd(&hist[d >> 8], 1);
    }
    __syncthreads();

    // pass B: reserve global run per bucket
    for (int j = tid; j < 512; j += 256) {
        int cc = hist[j];
        hbase[j] = cc ? atomicAdd(&gcur[j], cc) : 0;
    }

    // pass C: exclusive scan of hist -> lofs (512 bins, 256 threads)
    int a0 = hist[2 * tid], a1 = hist[2 * tid + 1];
    ps[tid] = a0 + a1;
    __syncthreads();
    for (int off = 1; off < 256; off <<= 1) {
        int t = (tid >= off) ? ps[tid - off] : 0;
        __syncthreads();
        ps[tid] += t;
        __syncthreads();
    }
    int ex = ps[tid] - (a0 + a1);
    lofs[2 * tid] = ex;
    lofs[2 * tid + 1] = ex + a0;
    __syncthreads();

    // pass D: scatter into LDS in bucket-sorted order
    for (int i = s0 + tid; i < s1; i += 256) {
        int s = load_idx(eidx, i, is64);
        int d = load_idx(eidx, (long)E + i, is64);
        int b = d >> 8;
        int loc = lofs[b] + atomicAdd(&cursor[b], 1);
        sorted[loc] = (unsigned)s | ((unsigned)(d & 255) << 17);
        sbuck[loc] = (unsigned short)b;
    }
    __syncthreads();

    // pass E: linear LDS read, coalesced run writes to global
    for (int i = tid; i < c; i += 256) {
        int b = sbuck[i];
        staging[hbase[b] + (i - lofs[b])] = sorted[i];
    }
}

// ---------- pass B: per-bucket local hist + scan -> rowstart/dinv, node-sorted ed ----------
__global__ void fine_kernel(const unsigned* __restrict__ staging,
                            const int* __restrict__ bucketbase, int n, int E,
                            int* __restrict__ ed, int* __restrict__ rowstart,
                            float* __restrict__ dinv) {
    __shared__ int lcnt[256];
    __shared__ int lofs[256];
    __shared__ int lcur[256];
    int tid = threadIdx.x;
    int b = blockIdx.x;
    int node0 = b << 8;
    int start = bucketbase[b], end = bucketbase[b + 1];
    int cnt = end - start;
    lcnt[tid] = 0;
    lcur[tid] = 0;
    __syncthreads();
    for (int i = tid; i < cnt; i += 256) {
        unsigned w = staging[start + i];
        atomicAdd(&lcnt[w >> 17], 1);
    }
    __syncthreads();
    int val = lcnt[tid];
    lofs[tid] = val;
    __syncthreads();
    for (int off = 1; off < 256; off <<= 1) {
        int t = (tid >= off) ? lofs[tid - off] : 0;
        __syncthreads();
        lofs[tid] += t;
        __syncthreads();
    }
    int ex = lofs[tid] - val;
    __syncthreads();
    lofs[tid] = ex;
    __syncthreads();
    int node = node0 + tid;
    if (node < n) {
        rowstart[node] = start + ex;
        dinv[node] = rsqrtf((float)(val + 1));
    }
    if (node == 0) rowstart[n] = E;
    for (int i = tid; i < cnt; i += 256) {
        unsigned w = staging[start + i];
        int ld = (int)(w >> 17);
        int pos = start + lofs[ld] + atomicAdd(&lcur[ld], 1);
        ed[pos] = (int)(w & 0x1FFFFu);
    }
}

// ---------- layer 0 dense transform: hw0 = bf16(dinv * (x @ W0)) ----------
__global__ void t0_kernel(const float* __restrict__ x, const float* __restrict__ W0,
                          const float* __restrict__ dinv,
                          __hip_bfloat16* __restrict__ hw, int n) {
    __shared__ float Wl[F_IN * H];
    int tid = threadIdx.x;
    for (int j = tid; j < F_IN * H; j += 256) Wl[j] = W0[j];
    __syncthreads();
    int g = tid >> 4, f = tid & 15;
    int v = blockIdx.x * NPB + g;
    if (v >= n) return;
    const float* xr = x + (long)v * F_IN;
    float acc = 0.f;
#pragma unroll
    for (int k = 0; k < F_IN; ++k) acc += xr[k] * Wl[k * H + f];
    hw[v * H + f] = __float2bfloat16(acc * dinv[v]);
}

// ---------- aggregation: node-parallel, 4 lanes/node x 4 features (ushort4) ----------
// hw holds dinv-scaled features (bf16); agg = dinv[v]*(sum_src hw[src] + hw[v])
__global__ __launch_bounds__(256) void agg_kernel(
    const int* __restrict__ ed, const int* __restrict__ rowstart,
    const float* __restrict__ dinv, const __hip_bfloat16* __restrict__ hw,
    const float* __restrict__ bias, const float* __restrict__ Wnext,
    float* __restrict__ jk, __hip_bfloat16* __restrict__ hw_next,
    int n, int first, int has_next) {
    __shared__ float Wl[H * H];
    int tid = threadIdx.x;
    if (has_next) Wl[tid] = Wnext[tid];  // 256 threads == 16x16
    __syncthreads();
    int g = tid >> 2, l = tid & 3;       // 64 nodes/block, 4 lanes/node
    int v = blockIdx.x * 64 + g;
    if (v >= n) return;                  // uniform per quad
    int fb = l * 4;                      // feature quad base
    const unsigned short* hwu = (const unsigned short*)hw;

    float4 accA = make_float4(0.f, 0.f, 0.f, 0.f);
    float4 accB = make_float4(0.f, 0.f, 0.f, 0.f);
    int s = rowstart[v], e = rowstart[v + 1];
    int i = s;
    for (; i + 8 <= e; i += 8) {
        int t0 = ed[i],     t1 = ed[i + 1], t2 = ed[i + 2], t3 = ed[i + 3];
        int t4 = ed[i + 4], t5 = ed[i + 5], t6 = ed[i + 6], t7 = ed[i + 7];
        ushort4 u0 = *(const ushort4*)(hwu + t0 * H + fb);
        ushort4 u1 = *(const ushort4*)(hwu + t1 * H + fb);
        ushort4 u2 = *(const ushort4*)(hwu + t2 * H + fb);
        ushort4 u3 = *(const ushort4*)(hwu + t3 * H + fb);
        ushort4 u4 = *(const ushort4*)(hwu + t4 * H + fb);
        ushort4 u5 = *(const ushort4*)(hwu + t5 * H + fb);
        ushort4 u6 = *(const ushort4*)(hwu + t6 * H + fb);
        ushort4 u7 = *(const ushort4*)(hwu + t7 * H + fb);
        accA.x += bfu2f(u0.x); accA.y += bfu2f(u0.y); accA.z += bfu2f(u0.z); accA.w += bfu2f(u0.w);
        accB.x += bfu2f(u1.x); accB.y += bfu2f(u1.y); accB.z += bfu2f(u1.z); accB.w += bfu2f(u1.w);
        accA.x += bfu2f(u2.x); accA.y += bfu2f(u2.y); accA.z += bfu2f(u2.z); accA.w += bfu2f(u2.w);
        accB.x += bfu2f(u3.x); accB.y += bfu2f(u3.y); accB.z += bfu2f(u3.z); accB.w += bfu2f(u3.w);
        accA.x += bfu2f(u4.x); accA.y += bfu2f(u4.y); accA.z += bfu2f(u4.z); accA.w += bfu2f(u4.w);
        accB.x += bfu2f(u5.x); accB.y += bfu2f(u5.y); accB.z += bfu2f(u5.z); accB.w += bfu2f(u5.w);
        accA.x += bfu2f(u6.x); accA.y += bfu2f(u6.y); accA.z += bfu2f(u6.z); accA.w += bfu2f(u6.w);
        accB.x += bfu2f(u7.x); accB.y += bfu2f(u7.y); accB.z += bfu2f(u7.z); accB.w += bfu2f(u7.w);
    }
    for (; i < e; ++i) {
        ushort4 u = *(const ushort4*)(hwu + ed[i] * H + fb);
        accA.x += bfu2f(u.x); accA.y += bfu2f(u.y); accA.z += bfu2f(u.z); accA.w += bfu2f(u.w);
    }

    // self-loop + bias + relu
    ushort4 us = *(const ushort4*)(hwu + (size_t)v * H + fb);
    float dv = dinv[v];
    float4 val;
    val.x = fmaxf((accA.x + accB.x + bfu2f(us.x)) * dv + bias[fb + 0], 0.f);
    val.y = fmaxf((accA.y + accB.y + bfu2f(us.y)) * dv + bias[fb + 1], 0.f);
    val.z = fmaxf((accA.z + accB.z + bfu2f(us.z)) * dv + bias[fb + 2], 0.f);
    val.w = fmaxf((accA.w + accB.w + bfu2f(us.w)) * dv + bias[fb + 3], 0.f);

    // jk running max (coalesced float4 per lane)
    float4* jkp = (float4*)(jk + (size_t)v * H + fb);
    float4 jv = val;
    if (!first) {
        float4 jo = *jkp;
        jv.x = fmaxf(jo.x, val.x); jv.y = fmaxf(jo.y, val.y);
        jv.z = fmaxf(jo.z, val.z); jv.w = fmaxf(jo.w, val.w);
    }
    *jkp = jv;

    // fused next-layer transform: out[f'] = sum_k val_all[k] * W[k][f']
    if (has_next) {
        float4 o = make_float4(0.f, 0.f, 0.f, 0.f);
#pragma unroll
        for (int kq = 0; kq < 4; ++kq) {
            float4 vk;
            vk.x = __shfl(val.x, kq, 4);
            vk.y = __shfl(val.y, kq, 4);
            vk.z = __shfl(val.z, kq, 4);
            vk.w = __shfl(val.w, kq, 4);
            float4 w0 = *(const float4*)(Wl + (4 * kq + 0) * H + fb);
            float4 w1 = *(const float4*)(Wl + (4 * kq + 1) * H + fb);
            float4 w2 = *(const float4*)(Wl + (4 * kq + 2) * H + fb);
            float4 w3 = *(const float4*)(Wl + (4 * kq + 3) * H + fb);
            o.x += vk.x * w0.x + vk.y * w1.x + vk.z * w2.x + vk.w * w3.x;
            o.y += vk.x * w0.y + vk.y * w1.y + vk.z * w2.y + vk.w * w3.y;
            o.z += vk.x * w0.z + vk.y * w1.z + vk.z * w2.z + vk.w * w3.z;
            o.w += vk.x * w0.w + vk.y * w1.w + vk.z * w2.w + vk.w * w3.w;
        }
        ushort4 ob;
        ob.x = (unsigned short)(__bfloat16_as_ushort(__float2bfloat16(o.x * dv)));
        ob.y = (unsigned short)(__bfloat16_as_ushort(__float2bfloat16(o.y * dv)));
        ob.z = (unsigned short)(__bfloat16_as_ushort(__float2bfloat16(o.z * dv)));
        ob.w = (unsigned short)(__bfloat16_as_ushort(__float2bfloat16(o.w * dv)));
        *(ushort4*)((unsigned short*)hw_next + (size_t)v * H + fb) = ob;
    }
}

// ---------- final FC: out = jk @ fc_w + fc_b ----------
__global__ void fc_kernel(const float* __restrict__ jk, const float* __restrict__ fc_w,
                          const float* __restrict__ fc_b, float* __restrict__ out, int n) {
    __shared__ float w[H];
    __shared__ float b0;
    if (threadIdx.x < H) w[threadIdx.x] = fc_w[threadIdx.x];
    if (threadIdx.x == 0) b0 = fc_b[0];
    __syncthreads();
    int v = blockIdx.x * 256 + threadIdx.x;
    if (v >= n) return;
    const float4* r = (const float4*)(jk + (long)v * H);
    float4 a = r[0], b = r[1], c = r[2], d = r[3];
    float sum = a.x * w[0] + a.y * w[1] + a.z * w[2] + a.w * w[3]
              + b.x * w[4] + b.y * w[5] + b.z * w[6] + b.w * w[7]
              + c.x * w[8] + c.y * w[9] + c.z * w[10] + c.w * w[11]
              + d.x * w[12] + d.y * w[13] + d.z * w[14] + d.w * w[15];
    out[v] = sum + b0;
}

extern "C" void kernel_launch(void* const* d_in, const int* in_sizes, int n_in,
                              void* d_out, int out_size, void* d_ws, size_t ws_size,
                              hipStream_t stream) {
    const float* x    = (const float*)d_in[0];
    const void*  eidx = d_in[1];
    const float* W0   = (const float*)d_in[2];
    const float* Ws   = (const float*)d_in[3];
    const float* bs   = (const float*)d_in[4];
    const float* fc_w = (const float*)d_in[5];
    const float* fc_b = (const float*)d_in[6];

    int n = in_sizes[0] / F_IN;        // 100000
    int E = in_sizes[1] / 2;           // 3200000
    int L = in_sizes[4] / H;           // 10

    // workspace carve-up
    char* w = (char*)d_ws;
    size_t off = 0;
    int* rowstart    = (int*)(w + off); off += align256((size_t)(n + 1) * 4);
    float* dinv      = (float*)(w + off); off += align256((size_t)n * 4);
    int* bucketcnt   = (int*)(w + off); off += align256(512 * 4);
    int* bucketbase  = (int*)(w + off); off += align256(513 * 4);
    int* gcur        = (int*)(w + off); off += align256(512 * 4);
    int* flag64      = (int*)(w + off); off += align256(256);
    unsigned* stg    = (unsigned*)(w + off); off += align256((size_t)E * 4);
    int* ed          = (int*)(w + off); off += align256((size_t)E * 4);
    __hip_bfloat16* hwA = (__hip_bfloat16*)(w + off); off += align256((size_t)n * H * 2);
    __hip_bfloat16* hwB = (__hip_bfloat16*)(w + off); off += align256((size_t)n * H * 2);
    float* jk        = (float*)(w + off); off += align256((size_t)n * H * 4);

    int NB = (n + 255) / 256;          // 391 buckets of 256 nodes

    hipMemsetAsync(bucketcnt, 0, 512 * 4, stream);
    detect_kernel<<<1, 256, 0, stream>>>((const int*)eidx, flag64);
    bcount_kernel<<<512, 256, 0, stream>>>(eidx, E, flag64, n, bucketcnt);
    bscan_kernel<<<1, 512, 0, stream>>>(bucketcnt, NB, E, gcur, bucketbase);
    int SG = (E + 6143) / 6144;        // chunk <= 6144 <= SCH
    stage_kernel<<<SG, 256, 0, stream>>>(eidx, E, flag64, n, gcur, stg);
    fine_kernel<<<NB, 256, 0, stream>>>(stg, bucketbase, n, E, ed, rowstart, dinv);

    int ngrid = (n + NPB - 1) / NPB;   // 6250
    t0_kernel<<<ngrid, 256, 0, stream>>>(x, W0, dinv, hwA, n);

    __hip_bfloat16* cur = hwA;
    __hip_bfloat16* nxt = hwB;
    int agrid = (n + 63) / 64;         // 1563
    for (int l = 0; l < L; ++l) {
        const float* bias  = bs + (size_t)l * H;
        const float* Wnext = (l < L - 1) ? (Ws + (size_t)l * H * H) : nullptr;
        agg_kernel<<<agrid, 256, 0, stream>>>(ed, rowstart, dinv, cur, bias, Wnext,
                                              jk, nxt, n, (l == 0) ? 1 : 0,
                                              (l < L - 1) ? 1 : 0);
        __hip_bfloat16* t = cur; cur = nxt; nxt = t;
    }

    fc_kernel<<<NB, 256, 0, stream>>>(jk, fc_w, fc_b, (float*)d_out, n);
}

// Round 6
// 359.098 us; speedup vs baseline: 9.9474x; 1.1518x over previous
//
#include <hip/hip_runtime.h>
#include <hip/hip_bf16.h>

#define H 16
#define F_IN 58
#define NPB 16     // nodes per block in t0 (256 threads / 16 lanes)
#define SCH 4160   // max edges per stage chunk (LDS sort capacity)
#define ECAP 4096  // LDS edge-cache capacity in agg (64 nodes * avg 32 = 2048 typ)

static inline size_t align256(size_t x) { return (x + 255) & ~(size_t)255; }

__device__ inline float bf2f(__hip_bfloat16 h) { return __bfloat162float(h); }
__device__ inline float bfu2f(unsigned short u) {
    return __uint_as_float(((unsigned)u) << 16);
}

// ---------- dtype detection: int64 vs int32 edge_index ----------
__global__ void detect_kernel(const int* eidx32, int* flag) {
    __shared__ int any;
    if (threadIdx.x == 0) any = 0;
    __syncthreads();
    int nz = 0;
    for (int j = threadIdx.x; j < 1024; j += 256)
        nz |= (eidx32[2 * j + 1] != 0);
    if (nz) atomicOr(&any, 1);
    __syncthreads();
    if (threadIdx.x == 0) *flag = (any == 0) ? 1 : 0;  // all-zero odd words -> int64
}

__device__ inline int load_idx(const void* eidx, long i, int is64) {
    if (is64) return (int)((const long long*)eidx)[i];
    return ((const int*)eidx)[i];
}

// ---------- bucket counts (391 bins of 256 nodes) via LDS histogram ----------
__global__ void bcount_kernel(const void* eidx, int E, const int* flag64,
                              int n, int* bucketcnt) {
    __shared__ int hist[512];
    int is64 = *flag64;
    int B = (n + 255) >> 8;
    int tid = threadIdx.x;
    for (int j = tid; j < B; j += 256) hist[j] = 0;
    __syncthreads();
    int stride = gridDim.x * blockDim.x;
    for (int i = blockIdx.x * blockDim.x + tid; i < E; i += stride) {
        int d = load_idx(eidx, (long)E + i, is64);
        atomicAdd(&hist[d >> 8], 1);
    }
    __syncthreads();
    for (int j = tid; j < B; j += 256)
        if (hist[j]) atomicAdd(&bucketcnt[j], hist[j]);
}

// ---------- exclusive scan of bucket counts (single block, B <= 512) ----------
__global__ void bscan_kernel(const int* bucketcnt, int B, int E,
                             int* gcur, int* bucketbase) {
    __shared__ int tmp[512];
    int tid = threadIdx.x;
    int val = (tid < B) ? bucketcnt[tid] : 0;
    tmp[tid] = val;
    __syncthreads();
    for (int off = 1; off < 512; off <<= 1) {
        int t = (tid >= off) ? tmp[tid - off] : 0;
        __syncthreads();
        tmp[tid] += t;
        __syncthreads();
    }
    if (tid < B) {
        int ex = tmp[tid] - val;
        gcur[tid] = ex;
        bucketbase[tid] = ex;
    }
    if (tid == 0) bucketbase[B] = E;
}

// ---------- stage: LDS counting-sort each chunk by bucket, write coalesced runs ----------
__global__ void stage_kernel(const void* eidx, int E, const int* flag64,
                             int n, int* gcur, unsigned* staging) {
    __shared__ unsigned sorted[SCH];
    __shared__ unsigned short sbuck[SCH];
    __shared__ int hist[512];
    __shared__ int hbase[512];
    __shared__ int lofs[512];
    __shared__ int cursor[512];
    __shared__ int ps[256];

    int is64 = *flag64;
    int tid = threadIdx.x;
    int chunk = (E + gridDim.x - 1) / gridDim.x;
    int s0 = blockIdx.x * chunk;
    int s1 = min(E, s0 + chunk);
    int c = s1 - s0;
    if (c <= 0) return;

    for (int j = tid; j < 512; j += 256) { hist[j] = 0; cursor[j] = 0; }
    __syncthreads();

    // pass A: per-chunk bucket histogram
    for (int i = s0 + tid; i < s1; i += 256) {
        int d = load_idx(eidx, (long)E + i, is64);
        atomicAdd(&hist[d >> 8], 1);
    }
    __syncthreads();

    // pass B: reserve global run per bucket
    for (int j = tid; j < 512; j += 256) {
        int cc = hist[j];
        hbase[j] = cc ? atomicAdd(&gcur[j], cc) : 0;
    }

    // pass C: exclusive scan of hist -> lofs (512 bins, 256 threads)
    int a0 = hist[2 * tid], a1 = hist[2 * tid + 1];
    ps[tid] = a0 + a1;
    __syncthreads();
    for (int off = 1; off < 256; off <<= 1) {
        int t = (tid >= off) ? ps[tid - off] : 0;
        __syncthreads();
        ps[tid] += t;
        __syncthreads();
    }
    int ex = ps[tid] - (a0 + a1);
    lofs[2 * tid] = ex;
    lofs[2 * tid + 1] = ex + a0;
    __syncthreads();

    // pass D: scatter into LDS in bucket-sorted order
    for (int i = s0 + tid; i < s1; i += 256) {
        int s = load_idx(eidx, i, is64);
        int d = load_idx(eidx, (long)E + i, is64);
        int b = d >> 8;
        int loc = lofs[b] + atomicAdd(&cursor[b], 1);
        sorted[loc] = (unsigned)s | ((unsigned)(d & 255) << 17);
        sbuck[loc] = (unsigned short)b;
    }
    __syncthreads();

    // pass E: linear LDS read, coalesced run writes to global
    for (int i = tid; i < c; i += 256) {
        int b = sbuck[i];
        staging[hbase[b] + (i - lofs[b])] = sorted[i];
    }
}

// ---------- per-bucket local hist + scan -> rowstart/dinv, node-sorted ed ----------
__global__ void fine_kernel(const unsigned* __restrict__ staging,
                            const int* __restrict__ bucketbase, int n, int E,
                            int* __restrict__ ed, int* __restrict__ rowstart,
                            float* __restrict__ dinv) {
    __shared__ int lcnt[256];
    __shared__ int lofs[256];
    __shared__ int lcur[256];
    int tid = threadIdx.x;
    int b = blockIdx.x;
    int node0 = b << 8;
    int start = bucketbase[b], end = bucketbase[b + 1];
    int cnt = end - start;
    lcnt[tid] = 0;
    lcur[tid] = 0;
    __syncthreads();
    for (int i = tid; i < cnt; i += 256) {
        unsigned w = staging[start + i];
        atomicAdd(&lcnt[w >> 17], 1);
    }
    __syncthreads();
    int val = lcnt[tid];
    lofs[tid] = val;
    __syncthreads();
    for (int off = 1; off < 256; off <<= 1) {
        int t = (tid >= off) ? lofs[tid - off] : 0;
        __syncthreads();
        lofs[tid] += t;
        __syncthreads();
    }
    int ex = lofs[tid] - val;
    __syncthreads();
    lofs[tid] = ex;
    __syncthreads();
    int node = node0 + tid;
    if (node < n) {
        rowstart[node] = start + ex;
        dinv[node] = rsqrtf((float)(val + 1));
    }
    if (node == 0) rowstart[n] = E;
    for (int i = tid; i < cnt; i += 256) {
        unsigned w = staging[start + i];
        int ld = (int)(w >> 17);
        int pos = start + lofs[ld] + atomicAdd(&lcur[ld], 1);
        ed[pos] = (int)(w & 0x1FFFFu);
    }
}

// ---------- layer 0 dense transform: hw0 = bf16(dinv * (x @ W0)) ----------
__global__ void t0_kernel(const float* __restrict__ x, const float* __restrict__ W0,
                          const float* __restrict__ dinv,
                          __hip_bfloat16* __restrict__ hw, int n) {
    __shared__ float Wl[F_IN * H];
    int tid = threadIdx.x;
    for (int j = tid; j < F_IN * H; j += 256) Wl[j] = W0[j];
    __syncthreads();
    int g = tid >> 4, f = tid & 15;
    int v = blockIdx.x * NPB + g;
    if (v >= n) return;
    const float* xr = x + (long)v * F_IN;
    float acc = 0.f;
#pragma unroll
    for (int k = 0; k < F_IN; ++k) acc += xr[k] * Wl[k * H + f];
    hw[v * H + f] = __float2bfloat16(acc * dinv[v]);
}

// ---------- aggregation: node-parallel, 4 lanes/node x 4 features, LDS edge cache ----------
// hw holds dinv-scaled features (bf16); agg = dinv[v]*(sum_src hw[src] + hw[v])
__global__ __launch_bounds__(256) void agg_kernel(
    const int* __restrict__ ed, const int* __restrict__ rowstart,
    const float* __restrict__ dinv, const __hip_bfloat16* __restrict__ hw,
    const float* __restrict__ bias, const float* __restrict__ Wnext,
    float* __restrict__ jk, __hip_bfloat16* __restrict__ hw_next,
    int n, int first, int has_next) {
    __shared__ float Wl[H * H];
    __shared__ int eds[ECAP];
    __shared__ int rs[65];
    int tid = threadIdx.x;
    if (has_next) Wl[tid] = Wnext[tid];  // 256 threads == 16x16
    int node0 = blockIdx.x * 64;
    int nn = min(64, n - node0);         // nodes in this block (>=1)
    if (tid <= nn) rs[tid] = rowstart[node0 + tid];
    __syncthreads();
    int s0 = rs[0];
    int cnt = rs[nn] - s0;
    for (int i = tid; i < cnt && i < ECAP; i += 256) eds[i] = ed[s0 + i];
    __syncthreads();

    int g = tid >> 2, l = tid & 3;       // 64 nodes/block, 4 lanes/node
    int v = node0 + g;
    if (g >= nn) return;
    int fb = l * 4;                      // feature quad base
    const unsigned short* hwu = (const unsigned short*)hw;

    float4 accA = make_float4(0.f, 0.f, 0.f, 0.f);
    float4 accB = make_float4(0.f, 0.f, 0.f, 0.f);
    int ls = rs[g] - s0, le = rs[g + 1] - s0;

    if (le <= ECAP) {                    // fast path: indices from LDS
        int i = ls;
        for (; i + 8 <= le; i += 8) {
            int t0 = eds[i],     t1 = eds[i + 1], t2 = eds[i + 2], t3 = eds[i + 3];
            int t4 = eds[i + 4], t5 = eds[i + 5], t6 = eds[i + 6], t7 = eds[i + 7];
            ushort4 u0 = *(const ushort4*)(hwu + t0 * H + fb);
            ushort4 u1 = *(const ushort4*)(hwu + t1 * H + fb);
            ushort4 u2 = *(const ushort4*)(hwu + t2 * H + fb);
            ushort4 u3 = *(const ushort4*)(hwu + t3 * H + fb);
            ushort4 u4 = *(const ushort4*)(hwu + t4 * H + fb);
            ushort4 u5 = *(const ushort4*)(hwu + t5 * H + fb);
            ushort4 u6 = *(const ushort4*)(hwu + t6 * H + fb);
            ushort4 u7 = *(const ushort4*)(hwu + t7 * H + fb);
            accA.x += bfu2f(u0.x); accA.y += bfu2f(u0.y); accA.z += bfu2f(u0.z); accA.w += bfu2f(u0.w);
            accB.x += bfu2f(u1.x); accB.y += bfu2f(u1.y); accB.z += bfu2f(u1.z); accB.w += bfu2f(u1.w);
            accA.x += bfu2f(u2.x); accA.y += bfu2f(u2.y); accA.z += bfu2f(u2.z); accA.w += bfu2f(u2.w);
            accB.x += bfu2f(u3.x); accB.y += bfu2f(u3.y); accB.z += bfu2f(u3.z); accB.w += bfu2f(u3.w);
            accA.x += bfu2f(u4.x); accA.y += bfu2f(u4.y); accA.z += bfu2f(u4.z); accA.w += bfu2f(u4.w);
            accB.x += bfu2f(u5.x); accB.y += bfu2f(u5.y); accB.z += bfu2f(u5.z); accB.w += bfu2f(u5.w);
            accA.x += bfu2f(u6.x); accA.y += bfu2f(u6.y); accA.z += bfu2f(u6.z); accA.w += bfu2f(u6.w);
            accB.x += bfu2f(u7.x); accB.y += bfu2f(u7.y); accB.z += bfu2f(u7.z); accB.w += bfu2f(u7.w);
        }
        for (; i < le; ++i) {
            ushort4 u = *(const ushort4*)(hwu + eds[i] * H + fb);
            accA.x += bfu2f(u.x); accA.y += bfu2f(u.y); accA.z += bfu2f(u.z); accA.w += bfu2f(u.w);
        }
    } else {                             // fallback: indices from global (huge block)
        int i = s0 + ls, e = s0 + le;
        for (; i + 8 <= e; i += 8) {
            int t0 = ed[i],     t1 = ed[i + 1], t2 = ed[i + 2], t3 = ed[i + 3];
            int t4 = ed[i + 4], t5 = ed[i + 5], t6 = ed[i + 6], t7 = ed[i + 7];
            ushort4 u0 = *(const ushort4*)(hwu + t0 * H + fb);
            ushort4 u1 = *(const ushort4*)(hwu + t1 * H + fb);
            ushort4 u2 = *(const ushort4*)(hwu + t2 * H + fb);
            ushort4 u3 = *(const ushort4*)(hwu + t3 * H + fb);
            ushort4 u4 = *(const ushort4*)(hwu + t4 * H + fb);
            ushort4 u5 = *(const ushort4*)(hwu + t5 * H + fb);
            ushort4 u6 = *(const ushort4*)(hwu + t6 * H + fb);
            ushort4 u7 = *(const ushort4*)(hwu + t7 * H + fb);
            accA.x += bfu2f(u0.x); accA.y += bfu2f(u0.y); accA.z += bfu2f(u0.z); accA.w += bfu2f(u0.w);
            accB.x += bfu2f(u1.x); accB.y += bfu2f(u1.y); accB.z += bfu2f(u1.z); accB.w += bfu2f(u1.w);
            accA.x += bfu2f(u2.x); accA.y += bfu2f(u2.y); accA.z += bfu2f(u2.z); accA.w += bfu2f(u2.w);
            accB.x += bfu2f(u3.x); accB.y += bfu2f(u3.y); accB.z += bfu2f(u3.z); accB.w += bfu2f(u3.w);
            accA.x += bfu2f(u4.x); accA.y += bfu2f(u4.y); accA.z += bfu2f(u4.z); accA.w += bfu2f(u4.w);
            accB.x += bfu2f(u5.x); accB.y += bfu2f(u5.y); accB.z += bfu2f(u5.z); accB.w += bfu2f(u5.w);
            accA.x += bfu2f(u6.x); accA.y += bfu2f(u6.y); accA.z += bfu2f(u6.z); accA.w += bfu2f(u6.w);
            accB.x += bfu2f(u7.x); accB.y += bfu2f(u7.y); accB.z += bfu2f(u7.z); accB.w += bfu2f(u7.w);
        }
        for (; i < e; ++i) {
            ushort4 u = *(const ushort4*)(hwu + ed[i] * H + fb);
            accA.x += bfu2f(u.x); accA.y += bfu2f(u.y); accA.z += bfu2f(u.z); accA.w += bfu2f(u.w);
        }
    }

    // self-loop + bias + relu
    ushort4 us = *(const ushort4*)(hwu + (size_t)v * H + fb);
    float dv = dinv[v];
    float4 val;
    val.x = fmaxf((accA.x + accB.x + bfu2f(us.x)) * dv + bias[fb + 0], 0.f);
    val.y = fmaxf((accA.y + accB.y + bfu2f(us.y)) * dv + bias[fb + 1], 0.f);
    val.z = fmaxf((accA.z + accB.z + bfu2f(us.z)) * dv + bias[fb + 2], 0.f);
    val.w = fmaxf((accA.w + accB.w + bfu2f(us.w)) * dv + bias[fb + 3], 0.f);

    // jk running max (coalesced float4 per lane)
    float4* jkp = (float4*)(jk + (size_t)v * H + fb);
    float4 jv = val;
    if (!first) {
        float4 jo = *jkp;
        jv.x = fmaxf(jo.x, val.x); jv.y = fmaxf(jo.y, val.y);
        jv.z = fmaxf(jo.z, val.z); jv.w = fmaxf(jo.w, val.w);
    }
    *jkp = jv;

    // fused next-layer transform: out[f'] = sum_k val_all[k] * W[k][f']
    if (has_next) {
        float4 o = make_float4(0.f, 0.f, 0.f, 0.f);
#pragma unroll
        for (int kq = 0; kq < 4; ++kq) {
            float4 vk;
            vk.x = __shfl(val.x, kq, 4);
            vk.y = __shfl(val.y, kq, 4);
            vk.z = __shfl(val.z, kq, 4);
            vk.w = __shfl(val.w, kq, 4);
            float4 w0 = *(const float4*)(Wl + (4 * kq + 0) * H + fb);
            float4 w1 = *(const float4*)(Wl + (4 * kq + 1) * H + fb);
            float4 w2 = *(const float4*)(Wl + (4 * kq + 2) * H + fb);
            float4 w3 = *(const float4*)(Wl + (4 * kq + 3) * H + fb);
            o.x += vk.x * w0.x + vk.y * w1.x + vk.z * w2.x + vk.w * w3.x;
            o.y += vk.x * w0.y + vk.y * w1.y + vk.z * w2.y + vk.w * w3.y;
            o.z += vk.x * w0.z + vk.y * w1.z + vk.z * w2.z + vk.w * w3.z;
            o.w += vk.x * w0.w + vk.y * w1.w + vk.z * w2.w + vk.w * w3.w;
        }
        ushort4 ob;
        ob.x = (unsigned short)(__bfloat16_as_ushort(__float2bfloat16(o.x * dv)));
        ob.y = (unsigned short)(__bfloat16_as_ushort(__float2bfloat16(o.y * dv)));
        ob.z = (unsigned short)(__bfloat16_as_ushort(__float2bfloat16(o.z * dv)));
        ob.w = (unsigned short)(__bfloat16_as_ushort(__float2bfloat16(o.w * dv)));
        *(ushort4*)((unsigned short*)hw_next + (size_t)v * H + fb) = ob;
    }
}

// ---------- final FC: out = jk @ fc_w + fc_b ----------
__global__ void fc_kernel(const float* __restrict__ jk, const float* __restrict__ fc_w,
                          const float* __restrict__ fc_b, float* __restrict__ out, int n) {
    __shared__ float w[H];
    __shared__ float b0;
    if (threadIdx.x < H) w[threadIdx.x] = fc_w[threadIdx.x];
    if (threadIdx.x == 0) b0 = fc_b[0];
    __syncthreads();
    int v = blockIdx.x * 256 + threadIdx.x;
    if (v >= n) return;
    const float4* r = (const float4*)(jk + (long)v * H);
    float4 a = r[0], b = r[1], c = r[2], d = r[3];
    float sum = a.x * w[0] + a.y * w[1] + a.z * w[2] + a.w * w[3]
              + b.x * w[4] + b.y * w[5] + b.z * w[6] + b.w * w[7]
              + c.x * w[8] + c.y * w[9] + c.z * w[10] + c.w * w[11]
              + d.x * w[12] + d.y * w[13] + d.z * w[14] + d.w * w[15];
    out[v] = sum + b0;
}

extern "C" void kernel_launch(void* const* d_in, const int* in_sizes, int n_in,
                              void* d_out, int out_size, void* d_ws, size_t ws_size,
                              hipStream_t stream) {
    const float* x    = (const float*)d_in[0];
    const void*  eidx = d_in[1];
    const float* W0   = (const float*)d_in[2];
    const float* Ws   = (const float*)d_in[3];
    const float* bs   = (const float*)d_in[4];
    const float* fc_w = (const float*)d_in[5];
    const float* fc_b = (const float*)d_in[6];

    int n = in_sizes[0] / F_IN;        // 100000
    int E = in_sizes[1] / 2;           // 3200000
    int L = in_sizes[4] / H;           // 10

    // workspace carve-up
    char* w = (char*)d_ws;
    size_t off = 0;
    int* rowstart    = (int*)(w + off); off += align256((size_t)(n + 1) * 4);
    float* dinv      = (float*)(w + off); off += align256((size_t)n * 4);
    int* bucketcnt   = (int*)(w + off); off += align256(512 * 4);
    int* bucketbase  = (int*)(w + off); off += align256(513 * 4);
    int* gcur        = (int*)(w + off); off += align256(512 * 4);
    int* flag64      = (int*)(w + off); off += align256(256);
    unsigned* stg    = (unsigned*)(w + off); off += align256((size_t)E * 4);
    int* ed          = (int*)(w + off); off += align256((size_t)E * 4);
    __hip_bfloat16* hwA = (__hip_bfloat16*)(w + off); off += align256((size_t)n * H * 2);
    __hip_bfloat16* hwB = (__hip_bfloat16*)(w + off); off += align256((size_t)n * H * 2);
    float* jk        = (float*)(w + off); off += align256((size_t)n * H * 4);

    int NB = (n + 255) / 256;          // 391 buckets of 256 nodes

    hipMemsetAsync(bucketcnt, 0, 512 * 4, stream);
    detect_kernel<<<1, 256, 0, stream>>>((const int*)eidx, flag64);
    bcount_kernel<<<512, 256, 0, stream>>>(eidx, E, flag64, n, bucketcnt);
    bscan_kernel<<<1, 512, 0, stream>>>(bucketcnt, NB, E, gcur, bucketbase);
    int SG = (E + 4095) / 4096;        // chunk <= 4096 <= SCH
    stage_kernel<<<SG, 256, 0, stream>>>(eidx, E, flag64, n, gcur, stg);
    fine_kernel<<<NB, 256, 0, stream>>>(stg, bucketbase, n, E, ed, rowstart, dinv);

    int ngrid = (n + NPB - 1) / NPB;   // 6250
    t0_kernel<<<ngrid, 256, 0, stream>>>(x, W0, dinv, hwA, n);

    __hip_bfloat16* cur = hwA;
    __hip_bfloat16* nxt = hwB;
    int agrid = (n + 63) / 64;         // 1563
    for (int l = 0; l < L; ++l) {
        const float* bias  = bs + (size_t)l * H;
        const float* Wnext = (l < L - 1) ? (Ws + (size_t)l * H * H) : nullptr;
        agg_kernel<<<agrid, 256, 0, stream>>>(ed, rowstart, dinv, cur, bias, Wnext,
                                              jk, nxt, n, (l == 0) ? 1 : 0,
                                              (l < L - 1) ? 1 : 0);
        __hip_bfloat16* t = cur; cur = nxt; nxt = t;
    }

    fc_kernel<<<NB, 256, 0, stream>>>(jk, fc_w, fc_b, (float*)d_out, n);
}